// Round 1
// baseline (1291.771 us; speedup 1.0000x reference)
//
#include <hip/hip_runtime.h>

// Problem constants
#define NB    8        // batches
#define NPT   16384    // points per batch
#define TILE  16       // points per block
#define NTH   256      // threads per block
#define GRIDX ((NB * NPT) / TILE)   // 8192 blocks

struct Params {
    const float* lr;     // [B,2,64,64]
    const float* ctx;    // [B,32,64,64]
    const float* eps;    // [B,64,64]
    const float* coord;  // [B,N,2]
    const float* W0; const float* B0;
    const float* W1; const float* B1;
    const float* W2; const float* B2;
    const float* W3; const float* B3;
    const float* W4; const float* B4;
    const float* W5; const float* B5;
    const float* W6; const float* B6;
    float* out;          // [B,N,2]
};

// Generic dense layer: out[t][n] = act( bias[n] + sum_k hin[t][k]*W[k][n]
//                                       (+ sum_j xin[t][j]*W[K_H+j][n]) )
// Thread mapping: each thread handles one output neuron n for a chunk of
// TP=8 points. W loads are lane-coalesced (consecutive n); LDS activation
// reads are wave-broadcast (same address across lanes).
template<int K_H, int N_OUT, int S_IN, int S_OUT, bool XIN, bool RELU>
__device__ __forceinline__ void layer(const float* __restrict__ W,
                                      const float* __restrict__ bias,
                                      const float* __restrict__ hin,
                                      const float* __restrict__ xin,
                                      float* __restrict__ outp,
                                      int tid)
{
    constexpr int TP    = 8;
    constexpr int NCH   = TILE / TP;        // 2 point-chunks
    constexpr int TOTAL = NCH * N_OUT;
    for (int e = tid; e < TOTAL; e += NTH) {
        const int n  = e % N_OUT;
        const int t0 = (e / N_OUT) * TP;
        float acc[TP];
        const float bv = bias[n];
#pragma unroll
        for (int tt = 0; tt < TP; ++tt) acc[tt] = bv;
        const float* wp = W + n;
        if (K_H > 0) {
#pragma unroll 8
            for (int k = 0; k < K_H; ++k) {
                const float w = wp[k * N_OUT];
#pragma unroll
                for (int tt = 0; tt < TP; ++tt)
                    acc[tt] = fmaf(hin[(t0 + tt) * S_IN + k], w, acc[tt]);
            }
        }
        if (XIN) {
#pragma unroll 8
            for (int k = 0; k < 37; ++k) {
                const float w = wp[(K_H + k) * N_OUT];
#pragma unroll
                for (int tt = 0; tt < TP; ++tt)
                    acc[tt] = fmaf(xin[(t0 + tt) * 37 + k], w, acc[tt]);
            }
        }
#pragma unroll
        for (int tt = 0; tt < TP; ++tt) {
            float v = RELU ? fmaxf(acc[tt], 0.0f) : acc[tt];
            outp[(t0 + tt) * S_OUT + n] = v;
        }
    }
}

__global__ __launch_bounds__(NTH, 3)
void cont_decoder_kernel(Params p)
{
    __shared__ float s_xin [TILE * 37];   // per-point 37-feature input
    __shared__ float s_bufA[TILE * 516];  // h0 / h2 / h4
    __shared__ float s_bufB[TILE * 256];  // h1 / h3 / h5
    __shared__ int   s_x0[TILE];
    __shared__ int   s_y0[TILE];
    __shared__ float s_wx[TILE];
    __shared__ float s_wy[TILE];

    const int tid = threadIdx.x;
    const int p0  = blockIdx.x * TILE;    // global point base (block-uniform batch)
    const int b   = p0 >> 14;             // NPT = 16384 points per batch

    // ---- Phase 1: per-point bilinear params + coord features ----
    if (tid < TILE) {
        const int pt = p0 + tid;
        const float cx = p.coord[2 * pt];
        const float cy = p.coord[2 * pt + 1];
        // align_corners=False: g = (c+1)*size/2 - 0.5, size = 64
        const float gx = (cx + 1.0f) * 32.0f - 0.5f;
        const float gy = (cy + 1.0f) * 32.0f - 0.5f;
        const float fx0 = floorf(gx);
        const float fy0 = floorf(gy);
        s_x0[tid] = (int)fx0;
        s_y0[tid] = (int)fy0;
        s_wx[tid] = gx - fx0;
        s_wy[tid] = gy - fy0;
        s_xin[tid * 37 + 32] = cx;
        s_xin[tid * 37 + 33] = cy;
    }
    __syncthreads();

    // ---- Phase 2: sample 35 channels per point ----
    // Reference swaps spatial axes before grid_sample: value = grid[b,c,x,y]
    // with x derived from coord[...,0] (gx) and y from coord[...,1] (gy).
    for (int idx = tid; idx < TILE * 35; idx += NTH) {
        const int t = idx / 35;
        const int c = idx % 35;
        const float* base;
        int col;
        if (c < 32)      { base = p.ctx + (size_t)(b * 32 + c) * 4096;        col = c; }
        else if (c < 34) { base = p.lr  + (size_t)(b * 2 + (c - 32)) * 4096;  col = 34 + (c - 32); }
        else             { base = p.eps + (size_t)b * 4096;                    col = 36; }

        const int   x0 = s_x0[t], y0 = s_y0[t];
        const float wx = s_wx[t], wy = s_wy[t];
        const int x1 = x0 + 1, y1 = y0 + 1;
        const bool xv0 = (x0 >= 0) & (x0 < 64);
        const bool xv1 = (x1 >= 0) & (x1 < 64);
        const bool yv0 = (y0 >= 0) & (y0 < 64);
        const bool yv1 = (y1 >= 0) & (y1 < 64);
        const int xc0 = min(max(x0, 0), 63), xc1 = min(max(x1, 0), 63);
        const int yc0 = min(max(y0, 0), 63), yc1 = min(max(y1, 0), 63);

        const float w00 = (1.0f - wx) * (1.0f - wy) * ((xv0 && yv0) ? 1.0f : 0.0f);
        const float w10 = wx * (1.0f - wy)          * ((xv1 && yv0) ? 1.0f : 0.0f);
        const float w01 = (1.0f - wx) * wy          * ((xv0 && yv1) ? 1.0f : 0.0f);
        const float w11 = wx * wy                   * ((xv1 && yv1) ? 1.0f : 0.0f);

        const float val = w00 * base[xc0 * 64 + yc0]
                        + w10 * base[xc1 * 64 + yc0]
                        + w01 * base[xc0 * 64 + yc1]
                        + w11 * base[xc1 * 64 + yc1];
        s_xin[t * 37 + col] = val;
    }
    __syncthreads();

    // ---- MLP: x_in(37) -> 516 -> 256 -> 128 -> 64 -> 32 -> 16 -> 2 ----
    // Layers 1..5 take [h_prev, x_in] (concat in that order).
    layer<0,   516, 37,  516, true,  true >(p.W0, p.B0, s_xin,  s_xin, s_bufA, tid);
    __syncthreads();
    layer<516, 256, 516, 256, true,  true >(p.W1, p.B1, s_bufA, s_xin, s_bufB, tid);
    __syncthreads();
    layer<256, 128, 256, 128, true,  true >(p.W2, p.B2, s_bufB, s_xin, s_bufA, tid);
    __syncthreads();
    layer<128, 64,  128, 64,  true,  true >(p.W3, p.B3, s_bufA, s_xin, s_bufB, tid);
    __syncthreads();
    layer<64,  32,  64,  32,  true,  true >(p.W4, p.B4, s_bufB, s_xin, s_bufA, tid);
    __syncthreads();
    layer<32,  16,  32,  16,  true,  true >(p.W5, p.B5, s_bufA, s_xin, s_bufB, tid);
    __syncthreads();
    layer<16,  2,   16,  2,   false, false>(p.W6, p.B6, s_bufB, s_xin,
                                            p.out + (size_t)p0 * 2, tid);
}

extern "C" void kernel_launch(void* const* d_in, const int* in_sizes, int n_in,
                              void* d_out, int out_size, void* d_ws, size_t ws_size,
                              hipStream_t stream)
{
    Params p;
    p.lr    = (const float*)d_in[0];
    p.ctx   = (const float*)d_in[1];
    p.eps   = (const float*)d_in[2];
    p.coord = (const float*)d_in[3];
    p.W0 = (const float*)d_in[4];  p.B0 = (const float*)d_in[5];
    p.W1 = (const float*)d_in[6];  p.B1 = (const float*)d_in[7];
    p.W2 = (const float*)d_in[8];  p.B2 = (const float*)d_in[9];
    p.W3 = (const float*)d_in[10]; p.B3 = (const float*)d_in[11];
    p.W4 = (const float*)d_in[12]; p.B4 = (const float*)d_in[13];
    p.W5 = (const float*)d_in[14]; p.B5 = (const float*)d_in[15];
    p.W6 = (const float*)d_in[16]; p.B6 = (const float*)d_in[17];
    p.out = (float*)d_out;

    hipLaunchKernelGGL(cont_decoder_kernel, dim3(GRIDX), dim3(NTH), 0, stream, p);
}

// Round 2
// 242.217 us; speedup vs baseline: 5.3331x; 5.3331x over previous
//
#include <hip/hip_runtime.h>

// ============================================================================
// ContDecoder on MI355X — bf16 MFMA version.
//
// Structure:
//   Kernel 1 (pack_weights): fp32 -> bf16 repack of all 7 layer weights into
//     MFMA B-fragment order in d_ws. Fragment (n_tile, k_step, lane) holds 8
//     contiguous bf16 = B[k_step*32 + (lane>>4)*8 + j][n_tile*16 + (lane&15)],
//     zero-padded (K to x32 per segment, N to x16). Padding-as-zeros makes the
//     [h, x_in] concat and all ragged dims free.
//   Kernel 2 (cont_decoder_mfma): 32 points/block, 256 thr (4 waves).
//     Bilinear-sample 35 chans + coords -> bf16 x_in in LDS, then 7 layers of
//     16x16x32 bf16 MFMA. Waves partition n-tiles (B frag loaded once/block,
//     reused across both m-tiles); A frags from LDS rows.
//
// LDS row layout per point (bf16 elems): [xin 0..64 | hA 64..608 | hB 608..864]
// stride 872 (dword stride 436 === 20 mod 32 -> 2-way bank aliasing, free).
// Layer sequence:  xin(37p64) ->W0-> hA(516p544) ->W1-> hB(256) ->W2-> hA(128)
//   ->W3-> hB(64) ->W4-> hA(32) ->W5-> hB(16) ->W6-> out(2). Stale bytes in
//   reused regions are always masked by zero-packed weight rows.
// ============================================================================

#define NTH     256
#define NWAVES  4
#define MPTS    32              // points per block (2 m-tiles of 16)
#define SROW    872             // LDS row stride in bf16 elems
#define XIN_OFF 0
#define HA_OFF  64
#define HB_OFF  608
#define NPOINTS (8 * 16384)
#define GRIDX   (NPOINTS / MPTS)   // 4096 blocks

typedef short          short8 __attribute__((ext_vector_type(8)));
typedef float          f32x4  __attribute__((ext_vector_type(4)));
typedef unsigned short u16;

__device__ __forceinline__ u16 f2bf(float f) {
    unsigned int u = __builtin_bit_cast(unsigned int, f);
    u += 0x7fffu + ((u >> 16) & 1u);        // round-to-nearest-even
    return (u16)(u >> 16);
}

// ---------------------------------------------------------------------------
// Packed-weight geometry (elems). ks = k-steps of 32; elems = nt*ks*512.
//   l : KHpad KSteps Ntiles  base
//   0 :    0    2     33        0      (xin-only, K=64)
//   1 :  544   19     16    33792
//   2 :  256   10      8   189440
//   3 :  128    6      4   230400
//   4 :   64    4      2   242688
//   5 :   32    3      1   246784
//   6 :   32    1      1   248320     total 248832 elems = 497664 B in d_ws
// ---------------------------------------------------------------------------
__constant__ int pk_base[8] = {0, 33792, 189440, 230400, 242688, 246784, 248320, 248832};
__constant__ int pk_ks[7]   = {2, 19, 10, 6, 4, 3, 1};
__constant__ int pk_khp[7]  = {0, 544, 256, 128, 64, 32, 32};
__constant__ int pk_kact[7] = {0, 516, 256, 128, 64, 32, 16};
__constant__ int pk_nact[7] = {516, 256, 128, 64, 32, 16, 2};

struct WPtrs { const float* W[7]; };

__global__ void pack_weights(WPtrs wp, u16* __restrict__ out)
{
    const int gid = blockIdx.x * blockDim.x + threadIdx.x;
    if (gid >= 248832) return;
    int l = 0;
    while (l < 6 && gid >= pk_base[l + 1]) ++l;
    const int r    = gid - pk_base[l];
    const int j    = r & 7;
    const int lane = (r >> 3) & 63;
    const int t    = r >> 9;
    const int ks   = pk_ks[l];
    const int s    = t % ks;
    const int nt   = t / ks;
    const int k    = s * 32 + (lane >> 4) * 8 + j;
    const int n    = nt * 16 + (lane & 15);
    const int nact = pk_nact[l];
    float v = 0.0f;
    if (n < nact) {
        if (k < pk_khp[l]) {                       // hidden segment
            if (k < pk_kact[l]) v = wp.W[l][k * nact + n];
        } else {                                    // x_in segment (37 rows)
            const int xr = k - pk_khp[l];
            if (xr < 37) v = wp.W[l][(pk_kact[l] + xr) * nact + n];
        }
    }
    out[gid] = f2bf(v);
}

// ---------------------------------------------------------------------------
// One MLP layer on a 32-point LDS tile.
// A-frag: lane holds act[m = mtile*16 + (lane&15)][k0 + (lane>>4)*8 + j]
// B-frag: packed, lane holds W[k0 + (lane>>4)*8 + j][ntile*16 + (lane&15)]
// D:      lane holds out[m = (lane>>4)*4 + r][n = lane&15]   (m89-verified)
// ---------------------------------------------------------------------------
template<int KHP, int HSEG, int OSEG, int NT, int NG, int NACT, int LBASE,
         bool XIN, bool RELU, bool GOUT>
__device__ __forceinline__ void mlayer(const u16* __restrict__ wpack,
                                       const float* __restrict__ bias,
                                       u16* __restrict__ s_act,
                                       float* __restrict__ gout, int p0,
                                       int wave, int lane)
{
    constexpr int KHS  = KHP / 32;
    constexpr int KS   = KHS + (XIN ? 2 : 0);     // total k-steps of 32
    constexpr int NGRP = (NT + NG - 1) / NG;
    const int lm = lane & 15;
    const int lq = lane >> 4;
    const u16* arow0 = s_act + (0 * 16 + lm) * SROW + lq * 8;
    const u16* arow1 = s_act + (1 * 16 + lm) * SROW + lq * 8;
    const u16* wbase = wpack + LBASE + lane * 8;

    for (int g = wave; g < NGRP; g += NWAVES) {
        const int n0 = g * NG;
        f32x4 acc[NG][2];
#pragma unroll
        for (int t = 0; t < NG; ++t) {
            acc[t][0] = (f32x4){0.f, 0.f, 0.f, 0.f};
            acc[t][1] = (f32x4){0.f, 0.f, 0.f, 0.f};
        }
#pragma unroll
        for (int s = 0; s < KS; ++s) {
            const int ab = (s < KHS) ? (HSEG + s * 32)
                                     : (XIN_OFF + (s - KHS) * 32);
            const short8 a0 = *(const short8*)(arow0 + ab);
            const short8 a1 = *(const short8*)(arow1 + ab);
#pragma unroll
            for (int t = 0; t < NG; ++t) {
                const int nt = n0 + t;
                if ((NT % NG) && nt >= NT) break;
                const short8 b = *(const short8*)(wbase + (size_t)(nt * KS + s) * 512);
                acc[t][0] = __builtin_amdgcn_mfma_f32_16x16x32_bf16(a0, b, acc[t][0], 0, 0, 0);
                acc[t][1] = __builtin_amdgcn_mfma_f32_16x16x32_bf16(a1, b, acc[t][1], 0, 0, 0);
            }
        }
#pragma unroll
        for (int t = 0; t < NG; ++t) {
            const int nt = n0 + t;
            if ((NT % NG) && nt >= NT) break;
            const int n = nt * 16 + lm;
            const float bv = (n < NACT) ? bias[n] : 0.f;   // pad neurons -> 0
#pragma unroll
            for (int m = 0; m < 2; ++m) {
#pragma unroll
                for (int r = 0; r < 4; ++r) {
                    float v = acc[t][m][r] + bv;
                    if (RELU) v = fmaxf(v, 0.f);
                    const int pt = m * 16 + lq * 4 + r;
                    if (GOUT) {
                        if (n < NACT)
                            gout[(size_t)(p0 + pt) * 2 + n] = v;
                    } else {
                        s_act[pt * SROW + OSEG + n] = f2bf(v);
                    }
                }
            }
        }
    }
}

struct MainParams {
    const float* lr;     // [B,2,64,64]
    const float* ctx;    // [B,32,64,64]
    const float* eps;    // [B,64,64]
    const float* coord;  // [B,N,2]
    const float* Bb[7];  // biases (fp32)
    const u16*   wpack;  // packed bf16 weights in d_ws
    float*       out;    // [B,N,2]
};

__global__ __launch_bounds__(NTH, 2)
void cont_decoder_mfma(MainParams p)
{
    __shared__ u16   s_act[MPTS * SROW];   // 55808 elems = 54.5 KB
    __shared__ int   s_x0[MPTS], s_y0[MPTS];
    __shared__ float s_wx[MPTS], s_wy[MPTS];

    const int tid  = threadIdx.x;
    const int wave = tid >> 6;
    const int lane = tid & 63;
    const int p0   = blockIdx.x * MPTS;
    const int b    = p0 >> 14;             // 16384 points per batch

    // ---- zero the pad regions: xin[37..64) and hA[528..544) (row 592..608) ----
    for (int i = tid; i < MPTS * 43; i += NTH) {
        const int pt = i / 43, c = i % 43;
        const int col = (c < 27) ? (37 + c) : (592 + (c - 27));
        s_act[pt * SROW + col] = 0;
    }

    // ---- bilinear params + coord features ----
    if (tid < MPTS) {
        const int pt = p0 + tid;
        const float cx = p.coord[2 * pt];
        const float cy = p.coord[2 * pt + 1];
        const float gx = (cx + 1.0f) * 32.0f - 0.5f;   // align_corners=False
        const float gy = (cy + 1.0f) * 32.0f - 0.5f;
        const float fx0 = floorf(gx), fy0 = floorf(gy);
        s_x0[tid] = (int)fx0;
        s_y0[tid] = (int)fy0;
        s_wx[tid] = gx - fx0;
        s_wy[tid] = gy - fy0;
        s_act[tid * SROW + 32] = f2bf(cx);
        s_act[tid * SROW + 33] = f2bf(cy);
    }
    __syncthreads();

    // ---- sample 35 channels/point (ref swaps spatial axes: val = g[b,c,x,y]) ----
    for (int idx = tid; idx < MPTS * 35; idx += NTH) {
        const int t = idx / 35;
        const int c = idx % 35;
        const float* base;
        int col;
        if (c < 32)      { base = p.ctx + (size_t)(b * 32 + c) * 4096;       col = c; }
        else if (c < 34) { base = p.lr  + (size_t)(b * 2 + (c - 32)) * 4096; col = 34 + (c - 32); }
        else             { base = p.eps + (size_t)b * 4096;                   col = 36; }

        const int   x0 = s_x0[t], y0 = s_y0[t];
        const float wx = s_wx[t], wy = s_wy[t];
        const int x1 = x0 + 1, y1 = y0 + 1;
        const bool xv0 = (x0 >= 0) & (x0 < 64);
        const bool xv1 = (x1 >= 0) & (x1 < 64);
        const bool yv0 = (y0 >= 0) & (y0 < 64);
        const bool yv1 = (y1 >= 0) & (y1 < 64);
        const int xc0 = min(max(x0, 0), 63), xc1 = min(max(x1, 0), 63);
        const int yc0 = min(max(y0, 0), 63), yc1 = min(max(y1, 0), 63);

        const float w00 = (1.0f - wx) * (1.0f - wy) * ((xv0 && yv0) ? 1.0f : 0.0f);
        const float w10 = wx * (1.0f - wy)          * ((xv1 && yv0) ? 1.0f : 0.0f);
        const float w01 = (1.0f - wx) * wy          * ((xv0 && yv1) ? 1.0f : 0.0f);
        const float w11 = wx * wy                   * ((xv1 && yv1) ? 1.0f : 0.0f);

        const float val = w00 * base[xc0 * 64 + yc0]
                        + w10 * base[xc1 * 64 + yc0]
                        + w01 * base[xc0 * 64 + yc1]
                        + w11 * base[xc1 * 64 + yc1];
        s_act[t * SROW + col] = f2bf(val);
    }
    __syncthreads();

    // ---- MLP ----
    //       KHP  HSEG    OSEG    NT  NG NACT LBASE   XIN    RELU   GOUT
    mlayer<  0,  HA_OFF, HA_OFF, 33, 2, 516, 0,      true,  true,  false>(p.wpack, p.Bb[0], s_act, nullptr, p0, wave, lane);
    __syncthreads();
    mlayer<544,  HA_OFF, HB_OFF, 16, 4, 256, 33792,  true,  true,  false>(p.wpack, p.Bb[1], s_act, nullptr, p0, wave, lane);
    __syncthreads();
    mlayer<256,  HB_OFF, HA_OFF,  8, 2, 128, 189440, true,  true,  false>(p.wpack, p.Bb[2], s_act, nullptr, p0, wave, lane);
    __syncthreads();
    mlayer<128,  HA_OFF, HB_OFF,  4, 1,  64, 230400, true,  true,  false>(p.wpack, p.Bb[3], s_act, nullptr, p0, wave, lane);
    __syncthreads();
    mlayer< 64,  HB_OFF, HA_OFF,  2, 1,  32, 242688, true,  true,  false>(p.wpack, p.Bb[4], s_act, nullptr, p0, wave, lane);
    __syncthreads();
    mlayer< 32,  HA_OFF, HB_OFF,  1, 1,  16, 246784, true,  true,  false>(p.wpack, p.Bb[5], s_act, nullptr, p0, wave, lane);
    __syncthreads();
    mlayer< 32,  HB_OFF, 0,       1, 1,   2, 248320, false, false, true >(p.wpack, p.Bb[6], s_act, p.out,   p0, wave, lane);
}

extern "C" void kernel_launch(void* const* d_in, const int* in_sizes, int n_in,
                              void* d_out, int out_size, void* d_ws, size_t ws_size,
                              hipStream_t stream)
{
    WPtrs wp;
    for (int l = 0; l < 7; ++l) wp.W[l] = (const float*)d_in[4 + 2 * l];

    MainParams p;
    p.lr    = (const float*)d_in[0];
    p.ctx   = (const float*)d_in[1];
    p.eps   = (const float*)d_in[2];
    p.coord = (const float*)d_in[3];
    for (int l = 0; l < 7; ++l) p.Bb[l] = (const float*)d_in[5 + 2 * l];
    p.wpack = (const u16*)d_ws;
    p.out   = (float*)d_out;

    hipLaunchKernelGGL(pack_weights, dim3(972), dim3(NTH), 0, stream, wp, (u16*)d_ws);
    hipLaunchKernelGGL(cont_decoder_mfma, dim3(GRIDX), dim3(NTH), 0, stream, p);
}

// Round 3
// 226.753 us; speedup vs baseline: 5.6968x; 1.0682x over previous
//
#include <hip/hip_runtime.h>

// ============================================================================
// ContDecoder on MI355X — bf16 MFMA, round 3.
// MPTS=64 points/block, 1024 threads (16 waves), 112 KB dynamic LDS,
// 1 block/CU. Each wave owns an n-tile group across ALL 4 m-tiles:
// every packed-B fragment is loaded exactly once per block (halves L2
// traffic vs round 2) and feeds 4 independent MFMA chains (2x ILP).
//
// LDS row layout per point (bf16): [xin 0..64 | hA 64..608 | hB 608..864],
// stride 872 elems. Stale bytes in reused regions are masked by zero-packed
// weight rows; pad neurons get bias 0 so they write exact zeros.
// ============================================================================

#define NTH     1024
#define NWAVES  16
#define MPTS    64              // points per block (4 m-tiles of 16)
#define SROW    872             // LDS row stride in bf16 elems
#define XIN_OFF 0
#define HA_OFF  64
#define HB_OFF  608
#define NPOINTS (8 * 16384)
#define GRIDX   (NPOINTS / MPTS)   // 2048 blocks
#define LDSBYTES (MPTS * SROW * 2) // 111616

typedef short          short8 __attribute__((ext_vector_type(8)));
typedef float          f32x4  __attribute__((ext_vector_type(4)));
typedef unsigned short u16;

__device__ __forceinline__ u16 f2bf(float f) {
    unsigned int u = __builtin_bit_cast(unsigned int, f);
    u += 0x7fffu + ((u >> 16) & 1u);        // round-to-nearest-even
    return (u16)(u >> 16);
}

// ---------------------------------------------------------------------------
// Packed-weight geometry (16B fragments of 8 bf16). frag (l, nt, s, lane)
// holds B[s*32 + (lane>>4)*8 + j][nt*16 + (lane&15)], j=0..7, zero-padded.
//   l : KHpad KSteps Ntiles  frag_base
//   0 :    0    2     33        0
//   1 :  544   19     16     4224
//   2 :  256   10      8    23680
//   3 :  128    6      4    28800
//   4 :   64    4      2    30336
//   5 :   32    3      1    30848
//   6 :   32    1      1    31040   total 31104 frags = 497664 B in d_ws
// ---------------------------------------------------------------------------
__constant__ int pk_base8[8] = {0, 4224, 23680, 28800, 30336, 30848, 31040, 31104};
__constant__ int pk_ks[7]    = {2, 19, 10, 6, 4, 3, 1};
__constant__ int pk_khp[7]   = {0, 544, 256, 128, 64, 32, 32};
__constant__ int pk_kact[7]  = {0, 516, 256, 128, 64, 32, 16};
__constant__ int pk_nact[7]  = {516, 256, 128, 64, 32, 16, 2};

struct WPtrs { const float* W[7]; };

// One thread = one 16B fragment. Reads coalesce across lanes (consecutive n
// for fixed j,k); writes are perfectly coalesced 16B/lane.
__global__ void pack_weights(WPtrs wp, u16* __restrict__ out)
{
    const int f = blockIdx.x * blockDim.x + threadIdx.x;
    if (f >= 31104) return;
    int l = 0;
    while (l < 6 && f >= pk_base8[l + 1]) ++l;
    const int r    = f - pk_base8[l];
    const int lane = r & 63;
    const int t    = r >> 6;
    const int ks   = pk_ks[l];
    const int s    = t % ks;
    const int nt   = t / ks;
    const int n    = nt * 16 + (lane & 15);
    const int k0   = s * 32 + (lane >> 4) * 8;
    const int nact = pk_nact[l];
    const int khp  = pk_khp[l];
    const int kact = pk_kact[l];
    const float* W = wp.W[l];

    union { short8 v; u16 e[8]; } frag;
#pragma unroll
    for (int j = 0; j < 8; ++j) {
        const int k = k0 + j;
        float v = 0.0f;
        if (n < nact) {
            if (k < khp) {
                if (k < kact) v = W[k * nact + n];
            } else {
                const int xr = k - khp;
                if (xr < 37) v = W[(kact + xr) * nact + n];
            }
        }
        frag.e[j] = f2bf(v);
    }
    *(short8*)(out + (size_t)f * 8) = frag.v;
}

// ---------------------------------------------------------------------------
// One MLP layer. Unit = (n-group of NG tiles) x (m-group of MS tiles of 16
// points). Units strided across 16 waves. B frags from global (L2), A frags
// from LDS rows, D written back to LDS (or global for the last layer).
// C/D layout: row = (lane>>4)*4 + r, col = lane&15  (m89-verified).
// ---------------------------------------------------------------------------
template<int KHP, int HSEG, int OSEG, int NT, int NG, int MS, int NACT,
         int LBASE, bool XIN, bool RELU, bool GOUT>
__device__ __forceinline__ void mlayer(const u16* __restrict__ wpack,
                                       const float* __restrict__ bias,
                                       u16* __restrict__ s_act,
                                       float* __restrict__ gout, int p0,
                                       int wave, int lane)
{
    constexpr int KHS   = KHP / 32;
    constexpr int KS    = KHS + (XIN ? 2 : 0);
    constexpr int NGRP  = (NT + NG - 1) / NG;
    constexpr int MGRP  = 4 / MS;            // 4 m-tiles total
    constexpr int UNITS = NGRP * MGRP;
    const int lm = lane & 15;
    const int lq = lane >> 4;
    const u16* wbase = wpack + LBASE + lane * 8;

    for (int u = wave; u < UNITS; u += NWAVES) {
        const int gn = u % NGRP;
        const int gm = u / NGRP;
        const int n0 = gn * NG;
        const int m0 = gm * MS;

        const u16* arow[MS];
#pragma unroll
        for (int m = 0; m < MS; ++m)
            arow[m] = s_act + ((m0 + m) * 16 + lm) * SROW + lq * 8;

        f32x4 acc[NG][MS];
#pragma unroll
        for (int t = 0; t < NG; ++t)
#pragma unroll
            for (int m = 0; m < MS; ++m)
                acc[t][m] = (f32x4){0.f, 0.f, 0.f, 0.f};

#pragma unroll
        for (int s = 0; s < KS; ++s) {
            const int ab = (s < KHS) ? (HSEG + s * 32)
                                     : (XIN_OFF + (s - KHS) * 32);
            short8 a[MS];
#pragma unroll
            for (int m = 0; m < MS; ++m)
                a[m] = *(const short8*)(arow[m] + ab);
#pragma unroll
            for (int t = 0; t < NG; ++t) {
                const int nt = n0 + t;
                if ((NT % NG) && nt >= NT) break;
                const short8 b = *(const short8*)(wbase + (size_t)(nt * KS + s) * 512);
#pragma unroll
                for (int m = 0; m < MS; ++m)
                    acc[t][m] = __builtin_amdgcn_mfma_f32_16x16x32_bf16(a[m], b, acc[t][m], 0, 0, 0);
            }
        }

#pragma unroll
        for (int t = 0; t < NG; ++t) {
            const int nt = n0 + t;
            if ((NT % NG) && nt >= NT) break;
            const int n = nt * 16 + lm;
            const float bv = (n < NACT) ? bias[n] : 0.f;   // pad neurons -> 0
#pragma unroll
            for (int m = 0; m < MS; ++m) {
#pragma unroll
                for (int r = 0; r < 4; ++r) {
                    float v = acc[t][m][r] + bv;
                    if (RELU) v = fmaxf(v, 0.f);
                    const int pt = (m0 + m) * 16 + lq * 4 + r;
                    if (GOUT) {
                        if (n < NACT)
                            gout[(size_t)(p0 + pt) * 2 + n] = v;
                    } else {
                        s_act[pt * SROW + OSEG + n] = f2bf(v);
                    }
                }
            }
        }
    }
}

struct MainParams {
    const float* lr;     // [B,2,64,64]
    const float* ctx;    // [B,32,64,64]
    const float* eps;    // [B,64,64]
    const float* coord;  // [B,N,2]
    const float* Bb[7];  // biases (fp32)
    const u16*   wpack;  // packed bf16 weights in d_ws
    float*       out;    // [B,N,2]
};

__global__ __launch_bounds__(NTH, 4)
void cont_decoder_mfma(MainParams p)
{
    extern __shared__ u16 s_act[];         // MPTS*SROW bf16 = 111616 B
    __shared__ int   s_x0[MPTS], s_y0[MPTS];
    __shared__ float s_wx[MPTS], s_wy[MPTS];

    const int tid  = threadIdx.x;
    const int wave = tid >> 6;
    const int lane = tid & 63;
    const int p0   = blockIdx.x * MPTS;
    const int b    = p0 >> 14;             // 16384 points per batch

    // ---- zero pad regions: xin[37..64) and hA[528..544) (cols 592..608) ----
    for (int i = tid; i < MPTS * 43; i += NTH) {
        const int pt = i / 43, c = i % 43;
        const int col = (c < 27) ? (37 + c) : (592 + (c - 27));
        s_act[pt * SROW + col] = 0;
    }

    // ---- bilinear params + coord features ----
    if (tid < MPTS) {
        const int pt = p0 + tid;
        const float cx = p.coord[2 * pt];
        const float cy = p.coord[2 * pt + 1];
        const float gx = (cx + 1.0f) * 32.0f - 0.5f;   // align_corners=False
        const float gy = (cy + 1.0f) * 32.0f - 0.5f;
        const float fx0 = floorf(gx), fy0 = floorf(gy);
        s_x0[tid] = (int)fx0;
        s_y0[tid] = (int)fy0;
        s_wx[tid] = gx - fx0;
        s_wy[tid] = gy - fy0;
        s_act[tid * SROW + 32] = f2bf(cx);
        s_act[tid * SROW + 33] = f2bf(cy);
    }
    __syncthreads();

    // ---- sample 35 channels/point (ref swaps spatial axes: val = g[b,c,x,y]) ----
    for (int idx = tid; idx < MPTS * 35; idx += NTH) {
        const int t = idx / 35;
        const int c = idx % 35;
        const float* base;
        int col;
        if (c < 32)      { base = p.ctx + (size_t)(b * 32 + c) * 4096;       col = c; }
        else if (c < 34) { base = p.lr  + (size_t)(b * 2 + (c - 32)) * 4096; col = 34 + (c - 32); }
        else             { base = p.eps + (size_t)b * 4096;                   col = 36; }

        const int   x0 = s_x0[t], y0 = s_y0[t];
        const float wx = s_wx[t], wy = s_wy[t];
        const int x1 = x0 + 1, y1 = y0 + 1;
        const bool xv0 = (x0 >= 0) & (x0 < 64);
        const bool xv1 = (x1 >= 0) & (x1 < 64);
        const bool yv0 = (y0 >= 0) & (y0 < 64);
        const bool yv1 = (y1 >= 0) & (y1 < 64);
        const int xc0 = min(max(x0, 0), 63), xc1 = min(max(x1, 0), 63);
        const int yc0 = min(max(y0, 0), 63), yc1 = min(max(y1, 0), 63);

        const float w00 = (1.0f - wx) * (1.0f - wy) * ((xv0 && yv0) ? 1.0f : 0.0f);
        const float w10 = wx * (1.0f - wy)          * ((xv1 && yv0) ? 1.0f : 0.0f);
        const float w01 = (1.0f - wx) * wy          * ((xv0 && yv1) ? 1.0f : 0.0f);
        const float w11 = wx * wy                   * ((xv1 && yv1) ? 1.0f : 0.0f);

        const float val = w00 * base[xc0 * 64 + yc0]
                        + w10 * base[xc1 * 64 + yc0]
                        + w01 * base[xc0 * 64 + yc1]
                        + w11 * base[xc1 * 64 + yc1];
        s_act[t * SROW + col] = f2bf(val);
    }
    __syncthreads();

    // ---- MLP:  xin(37p64) ->W0-> hA(516p528) ->W1-> hB(256) ->W2-> hA(128)
    //            ->W3-> hB(64) ->W4-> hA(32) ->W5-> hB(16) ->W6-> out(2)
    //       KHP  HSEG    OSEG    NT  NG MS NACT LBASE(elems) XIN   RELU  GOUT
    mlayer<  0,  HA_OFF, HA_OFF, 33, 2, 4, 516, 0,      true,  true,  false>(p.wpack, p.Bb[0], s_act, nullptr, p0, wave, lane);
    __syncthreads();
    mlayer<544,  HA_OFF, HB_OFF, 16, 1, 4, 256, 33792,  true,  true,  false>(p.wpack, p.Bb[1], s_act, nullptr, p0, wave, lane);
    __syncthreads();
    mlayer<256,  HB_OFF, HA_OFF,  8, 1, 2, 128, 189440, true,  true,  false>(p.wpack, p.Bb[2], s_act, nullptr, p0, wave, lane);
    __syncthreads();
    mlayer<128,  HA_OFF, HB_OFF,  4, 1, 1,  64, 230400, true,  true,  false>(p.wpack, p.Bb[3], s_act, nullptr, p0, wave, lane);
    __syncthreads();
    mlayer< 64,  HB_OFF, HA_OFF,  2, 1, 1,  32, 242688, true,  true,  false>(p.wpack, p.Bb[4], s_act, nullptr, p0, wave, lane);
    __syncthreads();
    mlayer< 32,  HA_OFF, HB_OFF,  1, 1, 1,  16, 246784, true,  true,  false>(p.wpack, p.Bb[5], s_act, nullptr, p0, wave, lane);
    __syncthreads();
    mlayer< 32,  HB_OFF, 0,       1, 1, 1,   2, 248320, false, false, true >(p.wpack, p.Bb[6], s_act, p.out,   p0, wave, lane);
}

extern "C" void kernel_launch(void* const* d_in, const int* in_sizes, int n_in,
                              void* d_out, int out_size, void* d_ws, size_t ws_size,
                              hipStream_t stream)
{
    WPtrs wp;
    for (int l = 0; l < 7; ++l) wp.W[l] = (const float*)d_in[4 + 2 * l];

    MainParams p;
    p.lr    = (const float*)d_in[0];
    p.ctx   = (const float*)d_in[1];
    p.eps   = (const float*)d_in[2];
    p.coord = (const float*)d_in[3];
    for (int l = 0; l < 7; ++l) p.Bb[l] = (const float*)d_in[5 + 2 * l];
    p.wpack = (const u16*)d_ws;
    p.out   = (float*)d_out;

    // Opt in to >64 KB dynamic LDS (idempotent; not a stream op, capture-safe).
    hipFuncSetAttribute((const void*)cont_decoder_mfma,
                        hipFuncAttributeMaxDynamicSharedMemorySize, LDSBYTES);

    hipLaunchKernelGGL(pack_weights, dim3(122), dim3(256), 0, stream, wp, (u16*)d_ws);
    hipLaunchKernelGGL(cont_decoder_mfma, dim3(GRIDX), dim3(NTH), LDSBYTES, stream, p);
}